// Round 27
// baseline (198.448 us; speedup 1.0000x reference)
//
#include <hip/hip_runtime.h>
#include <math.h>

typedef unsigned short u16;
typedef __bf16 bf16x8 __attribute__((ext_vector_type(8)));
typedef float f32x4 __attribute__((ext_vector_type(4)));
typedef unsigned short u16x8 __attribute__((ext_vector_type(8)));

#define SLEN 2048
#define HIDN 2048
#define NH   16
#define DHD  128

static __device__ __forceinline__ float bf2f(u16 u) {
  unsigned int i = ((unsigned int)u) << 16;
  return __builtin_bit_cast(float, i);
}
static __device__ __forceinline__ u16 f2bf(float f) {
  unsigned int x = __builtin_bit_cast(unsigned int, f);
  unsigned int r = x + 0x7fffu + ((x >> 16) & 1u);
  return (u16)(r >> 16);
}
static __device__ __forceinline__ void gload_lds16(const u16* g, u16* l) {
  __builtin_amdgcn_global_load_lds((const __attribute__((address_space(1))) void*)g,
                                   (__attribute__((address_space(3))) void*)l,
                                   16, 0, 0);
}

// ---------------------------------------------------------------------------
// Fused prep: [0,3072) transpose+cvt w_qkv; [3072,4096) w_out; [4096,6144) hs.
// ---------------------------------------------------------------------------
__global__ __launch_bounds__(256) void prep(const float* __restrict__ wqkv,
                                            const float* __restrict__ wout,
                                            const float* __restrict__ hs,
                                            u16* __restrict__ wqkvT,
                                            u16* __restrict__ woutT,
                                            u16* __restrict__ hsB) {
  const int lin = blockIdx.x;
  const int t = threadIdx.x;
  if (lin >= 4096) {
    int i = ((lin - 4096) * 256 + t) * 8;
    f32x4 a = *(const f32x4*)&hs[i];
    f32x4 b = *(const f32x4*)&hs[i + 4];
    u16x8 v;
#pragma unroll
    for (int j = 0; j < 4; ++j) { v[j] = f2bf(a[j]); v[4 + j] = f2bf(b[j]); }
    *(u16x8*)&hsB[i] = v;
    return;
  }
  const float* in;
  u16* out;
  int istride, ostride, bx, by;
  if (lin < 3072) {
    in = wqkv; out = wqkvT; istride = 6144; ostride = 2048;
    bx = lin & 31; by = lin >> 5;
  } else {
    in = wout; out = woutT; istride = 2048; ostride = 2048;
    int idx = lin - 3072;
    bx = idx & 31; by = idx >> 5;
  }
  __shared__ float tl[64][65];
  const int r0 = bx * 64, c0 = by * 64;
#pragma unroll
  for (int it = 0; it < 4; ++it) {
    int row = it * 16 + (t >> 4);
    int col = (t & 15) * 4;
    f32x4 v = *(const f32x4*)&in[(size_t)(r0 + row) * istride + c0 + col];
    tl[row][col] = v[0]; tl[row][col + 1] = v[1];
    tl[row][col + 2] = v[2]; tl[row][col + 3] = v[3];
  }
  __syncthreads();
#pragma unroll
  for (int it = 0; it < 2; ++it) {
    int orow = it * 32 + (t >> 3);
    int ocol = (t & 7) * 8;
    u16x8 v;
#pragma unroll
    for (int j = 0; j < 8; ++j) v[j] = f2bf(tl[ocol + j][orow]);
    *(u16x8*)&out[(size_t)(c0 + orow) * ostride + r0 + ocol] = v;
  }
}

// ---------------------------------------------------------------------------
// XCD by-chunked block mapping (B-panels L2-resident per XCD).
// ---------------------------------------------------------------------------
static __device__ __forceinline__ void xcd_map(int lin, int N, int* pbx, int* pby) {
  const int nby = N >> 7;
  const int cby = nby >> 3;
  const int xcd = lin & 7, idx = lin >> 3;
  *pby = xcd * cby + (idx % cby);
  *pbx = idx / cby;
}

// ---------------------------------------------------------------------------
// MFMA GEMM single-buffer (3-blocks/CU regime).  C = A * BT^T + bias.
// ---------------------------------------------------------------------------
__global__ __launch_bounds__(256) void gemm_sb(const u16* __restrict__ A,
                                               const u16* __restrict__ BT,
                                               const float* __restrict__ bias,
                                               float* Cf, u16* Cb,
                                               int M, int N, int K) {
  int bx, by;
  xcd_map(blockIdx.x, N, &bx, &by);

  __shared__ u16 lA[128 * 64];
  __shared__ u16 lB[128 * 64];
  const int t = threadIdx.x;
  const int lane = t & 63, w = t >> 6;
  const int g = lane >> 4, l16 = lane & 15;
  const int wr = w >> 1, wc = w & 1;
  const u16* Ab = A + (size_t)bx * 128 * K;
  const u16* Bb = BT + (size_t)by * 128 * K;

  f32x4 acc[4][4];
#pragma unroll
  for (int mi = 0; mi < 4; ++mi)
#pragma unroll
    for (int ni = 0; ni < 4; ++ni) acc[mi][ni] = (f32x4)(0.0f);

  for (int k0 = 0; k0 < K; k0 += 64) {
    __syncthreads();
#pragma unroll
    for (int i = 0; i < 4; ++i) {
      int e = t * 8 + i * 2048;
      int row = e >> 6;
      int col16 = (e & 63) >> 3;
      int scol = (col16 ^ (row & 7)) * 8;
      gload_lds16(Ab + (size_t)row * K + k0 + scol, &lA[e]);
      gload_lds16(Bb + (size_t)row * K + k0 + scol, &lB[e]);
    }
    __syncthreads();
#pragma unroll
    for (int kk = 0; kk < 2; ++kk) {
      bf16x8 af[4], bfr[4];
#pragma unroll
      for (int mi = 0; mi < 4; ++mi) {
        int row = wr * 64 + mi * 16 + l16;
        af[mi] = *(const bf16x8*)&lA[row * 64 + (((4 * kk + g) ^ (l16 & 7)) << 3)];
      }
#pragma unroll
      for (int ni = 0; ni < 4; ++ni) {
        int row = wc * 64 + ni * 16 + l16;
        bfr[ni] = *(const bf16x8*)&lB[row * 64 + (((4 * kk + g) ^ (l16 & 7)) << 3)];
      }
#pragma unroll
      for (int mi = 0; mi < 4; ++mi)
#pragma unroll
        for (int ni = 0; ni < 4; ++ni)
          acc[mi][ni] = __builtin_amdgcn_mfma_f32_16x16x32_bf16(af[mi], bfr[ni],
                                                                acc[mi][ni], 0, 0, 0);
    }
  }

#pragma unroll
  for (int ni = 0; ni < 4; ++ni) {
    int n = by * 128 + wc * 64 + ni * 16 + l16;
    float bv = bias[n];
#pragma unroll
    for (int mi = 0; mi < 4; ++mi) {
      int m = bx * 128 + wr * 64 + mi * 16 + 4 * g;
#pragma unroll
      for (int r = 0; r < 4; ++r) {
        float v = acc[mi][ni][r] + bv;
        if (Cf) Cf[(size_t)(m + r) * N + n] = v;
        else    Cb[(size_t)(m + r) * N + n] = f2bf(v);
      }
    }
  }
}

// ---------------------------------------------------------------------------
// MFMA GEMM double-buffer 2-phase prefetch (1-block/CU regime; ~2x in r20).
// ---------------------------------------------------------------------------
__global__ __launch_bounds__(256) void gemm_db(const u16* __restrict__ A,
                                               const u16* __restrict__ BT,
                                               const float* __restrict__ bias,
                                               float* Cf, u16* Cb,
                                               int M, int N, int K) {
  int bx, by;
  xcd_map(blockIdx.x, N, &bx, &by);

  __shared__ u16 lA[2][128 * 64];
  __shared__ u16 lB[2][128 * 64];
  const int t = threadIdx.x;
  const int lane = t & 63, w = t >> 6;
  const int g = lane >> 4, l16 = lane & 15;
  const int wr = w >> 1, wc = w & 1;
  const u16* Ab = A + (size_t)bx * 128 * K;
  const u16* Bb = BT + (size_t)by * 128 * K;

  f32x4 acc[4][4];
#pragma unroll
  for (int mi = 0; mi < 4; ++mi)
#pragma unroll
    for (int ni = 0; ni < 4; ++ni) acc[mi][ni] = (f32x4)(0.0f);

#pragma unroll
  for (int i = 0; i < 4; ++i) {
    int e = t * 8 + i * 2048;
    int row = e >> 6;
    int col16 = (e & 63) >> 3;
    int scol = (col16 ^ (row & 7)) * 8;
    gload_lds16(Ab + (size_t)row * K + scol, &lA[0][e]);
    gload_lds16(Bb + (size_t)row * K + scol, &lB[0][e]);
  }
  __syncthreads();

  const int nk = K >> 6;
  int cur = 0;
  for (int kt = 0; kt < nk; ++kt) {
    if (kt + 1 < nk) {
      const int k1 = (kt + 1) << 6;
#pragma unroll
      for (int i = 0; i < 4; ++i) {
        int e = t * 8 + i * 2048;
        int row = e >> 6;
        int col16 = (e & 63) >> 3;
        int scol = (col16 ^ (row & 7)) * 8;
        gload_lds16(Ab + (size_t)row * K + k1 + scol, &lA[cur ^ 1][e]);
        gload_lds16(Bb + (size_t)row * K + k1 + scol, &lB[cur ^ 1][e]);
      }
    }
#pragma unroll
    for (int kk = 0; kk < 2; ++kk) {
      bf16x8 af[4], bfr[4];
#pragma unroll
      for (int mi = 0; mi < 4; ++mi) {
        int row = wr * 64 + mi * 16 + l16;
        af[mi] = *(const bf16x8*)&lA[cur][row * 64 + (((4 * kk + g) ^ (l16 & 7)) << 3)];
      }
#pragma unroll
      for (int ni = 0; ni < 4; ++ni) {
        int row = wc * 64 + ni * 16 + l16;
        bfr[ni] = *(const bf16x8*)&lB[cur][row * 64 + (((4 * kk + g) ^ (l16 & 7)) << 3)];
      }
#pragma unroll
      for (int mi = 0; mi < 4; ++mi)
#pragma unroll
        for (int ni = 0; ni < 4; ++ni)
          acc[mi][ni] = __builtin_amdgcn_mfma_f32_16x16x32_bf16(af[mi], bfr[ni],
                                                                acc[mi][ni], 0, 0, 0);
    }
    __syncthreads();
    cur ^= 1;
  }

#pragma unroll
  for (int ni = 0; ni < 4; ++ni) {
    int n = by * 128 + wc * 64 + ni * 16 + l16;
    float bv = bias[n];
#pragma unroll
    for (int mi = 0; mi < 4; ++mi) {
      int m = bx * 128 + wr * 64 + mi * 16 + 4 * g;
#pragma unroll
      for (int r = 0; r < 4; ++r) {
        float v = acc[mi][ni][r] + bv;
        if (Cf) Cf[(size_t)(m + r) * N + n] = v;
        else    Cb[(size_t)(m + r) * N + n] = f2bf(v);
      }
    }
  }
}

// ---------------------------------------------------------------------------
// Fused mid: [0,2048) rms_rope; [2048,3072) V transpose -> Vt[h][d][s].
// ---------------------------------------------------------------------------
__global__ __launch_bounds__(256) void mid(const u16* __restrict__ qkv,
                                           const float* __restrict__ fcos,
                                           const float* __restrict__ fsin,
                                           const float* __restrict__ wq,
                                           const float* __restrict__ wk,
                                           u16* __restrict__ Qr,
                                           u16* __restrict__ Kr,
                                           u16* __restrict__ Vt) {
  const int lin = blockIdx.x;
  const int t = threadIdx.x;

  if (lin >= 2048) {
    __shared__ u16 tl[64][72];
    int idx = lin - 2048;
    int bx = idx & 31;
    int byy = (idx >> 5) & 1;
    int z = idx >> 6;
    const u16* in = qkv + 4096 + (size_t)z * 128;
    u16* out = Vt + (size_t)z * 262144;
    const int r0 = bx * 64, c0 = byy * 64;
#pragma unroll
    for (int it = 0; it < 2; ++it) {
      int row = it * 32 + (t >> 3);
      int col = (t & 7) * 8;
      *(u16x8*)&tl[row][col] =
          *(const u16x8*)&in[(size_t)(r0 + row) * 6144 + c0 + col];
    }
    __syncthreads();
#pragma unroll
    for (int it = 0; it < 2; ++it) {
      int orow = it * 32 + (t >> 3);
      int ocol = (t & 7) * 8;
      u16x8 v;
#pragma unroll
      for (int j = 0; j < 8; ++j) v[j] = tl[ocol + j][orow];
      *(u16x8*)&out[(size_t)(c0 + orow) * 2048 + r0 + ocol] = v;
    }
    return;
  }

  const int s = lin;
  const int lane = t & 63, w = t >> 6;
  __shared__ float red[2][4];
  const u16* row = qkv + (size_t)s * (3 * HIDN);

  u16x8 xq = *(const u16x8*)&row[t * 8];
  u16x8 xk = *(const u16x8*)&row[HIDN + t * 8];
  float fq[8], fk[8];
  float ssq = 0.f, ssk = 0.f;
#pragma unroll
  for (int j = 0; j < 8; ++j) {
    fq[j] = bf2f(xq[j]); ssq += fq[j] * fq[j];
    fk[j] = bf2f(xk[j]); ssk += fk[j] * fk[j];
  }
#pragma unroll
  for (int off = 32; off >= 1; off >>= 1) {
    ssq += __shfl_xor(ssq, off);
    ssk += __shfl_xor(ssk, off);
  }
  if (lane == 0) { red[0][w] = ssq; red[1][w] = ssk; }
  __syncthreads();
  float sq = red[0][0] + red[0][1] + red[0][2] + red[0][3];
  float sk = red[1][0] + red[1][1] + red[1][2] + red[1][3];
  float rq = rsqrtf(sq / (float)HIDN + 1e-6f);
  float rk = rsqrtf(sk / (float)HIDN + 1e-6f);

  f32x4 wq0 = *(const f32x4*)&wq[t * 8];
  f32x4 wq1 = *(const f32x4*)&wq[t * 8 + 4];
  f32x4 wk0 = *(const f32x4*)&wk[t * 8];
  f32x4 wk1 = *(const f32x4*)&wk[t * 8 + 4];
  float wqa[8] = {wq0[0], wq0[1], wq0[2], wq0[3], wq1[0], wq1[1], wq1[2], wq1[3]};
  float wka[8] = {wk0[0], wk0[1], wk0[2], wk0[3], wk1[0], wk1[1], wk1[2], wk1[3]};
  const int c0 = t * 8;
  const int h = c0 >> 7;
  const int d0 = c0 & 127;
  const int i0 = d0 >> 1;
  const float* cp = fcos + (size_t)s * (DHD / 2) + i0;
  const float* sp = fsin + (size_t)s * (DHD / 2) + i0;
  const float qscale = 0.12751744925f;  // log2(e)/sqrt(128)

  u16x8 oq, ok;
#pragma unroll
  for (int p = 0; p < 4; ++p) {
    float c = cp[p], sn = sp[p];
    float q1 = fq[2 * p] * rq * wqa[2 * p];
    float q2 = fq[2 * p + 1] * rq * wqa[2 * p + 1];
    float k1 = fk[2 * p] * rk * wka[2 * p];
    float k2 = fk[2 * p + 1] * rk * wka[2 * p + 1];
    oq[2 * p]     = f2bf((q1 * c - q2 * sn) * qscale);
    oq[2 * p + 1] = f2bf((q1 * sn + q2 * c) * qscale);
    ok[2 * p]     = f2bf(k1 * c - k2 * sn);
    ok[2 * p + 1] = f2bf(k1 * sn + k2 * c);
  }
  size_t o = (size_t)h * SLEN * DHD + (size_t)s * DHD + d0;
  *(u16x8*)&Qr[o] = oq;
  *(u16x8*)&Kr[o] = ok;
}

// ---------------------------------------------------------------------------
// MFMA flash attention (r26 + deferred lsum reduction):
// K AND V LDS-staged (global_load_lds w16, XOR-swizzled, double-buffered,
// shared by 4 waves) + XCD-aware block mapping.  Swapped-operand QK^T ->
// lane-local softmax in exp2 domain.  Defer-max THR=8 (T13); packed b64 P
// writes; NEW: lsum kept as per-lane PARTIAL (own 16 kv values) -- the
// cross-lane reduce (2 shfl/tile) moves out of the loop to a single final
// 2-shfl reduce (valid since m/corr are row-uniform after the tm reduce).
// ---------------------------------------------------------------------------
__global__ __launch_bounds__(256) void attn_fwd(const u16* __restrict__ Qr,
                                                const u16* __restrict__ Kr,
                                                const u16* __restrict__ Vt,
                                                u16* __restrict__ out) {
  const int lin = blockIdx.x;
  const int xcd = lin & 7, idx = lin >> 3;
  const int h = xcd + ((idx >> 5) << 3);
  const int qb = idx & 31;
  const int t = threadIdx.x;
  const int lane = t & 63, w = t >> 6;
  const int g = lane >> 4, l16 = lane & 15;
  const int q0 = qb * 64 + w * 16;
  const u16* Qh = Qr + (size_t)h * SLEN * DHD;
  const u16* Kh = Kr + (size_t)h * SLEN * DHD;
  const u16* Vh = Vt + (size_t)h * DHD * SLEN;

  __shared__ u16 Kl[2][64 * 128];
  __shared__ u16 Vl[2][128 * 64];
  __shared__ u16 Pl[4][16][72];

  bf16x8 aq[4];
#pragma unroll
  for (int dk = 0; dk < 4; ++dk)
    aq[dk] = *(const bf16x8*)&Qh[(size_t)(q0 + l16) * DHD + dk * 32 + g * 8];

  f32x4 o[8];
#pragma unroll
  for (int df = 0; df < 8; ++df) o[df] = (f32x4)(0.0f);
  float m = -INFINITY, lsum = 0.f;   // lsum = per-lane PARTIAL (16 kv values)

#pragma unroll
  for (int i = 0; i < 4; ++i) {
    int e = t * 8 + i * 2048;
    int kr = e >> 7, kc = (e & 127) >> 3;
    gload_lds16(Kh + (size_t)kr * DHD + ((kc ^ (kr & 7)) << 3), &Kl[0][e]);
    int vr = e >> 6, vc = (e & 63) >> 3;
    gload_lds16(Vh + (size_t)vr * SLEN + ((vc ^ (vr & 7)) << 3), &Vl[0][e]);
  }
  __syncthreads();

  int cur = 0;
  for (int kt = 0; kt < SLEN / 64; ++kt) {
    if (kt + 1 < SLEN / 64) {
      const int kv1 = (kt + 1) * 64;
#pragma unroll
      for (int i = 0; i < 4; ++i) {
        int e = t * 8 + i * 2048;
        int kr = e >> 7, kc = (e & 127) >> 3;
        gload_lds16(Kh + (size_t)(kv1 + kr) * DHD + ((kc ^ (kr & 7)) << 3),
                    &Kl[cur ^ 1][e]);
        int vr = e >> 6, vc = (e & 63) >> 3;
        gload_lds16(Vh + (size_t)vr * SLEN + kv1 + ((vc ^ (vr & 7)) << 3),
                    &Vl[cur ^ 1][e]);
      }
    }

    f32x4 s4[4];
#pragma unroll
    for (int nf = 0; nf < 4; ++nf) s4[nf] = (f32x4)(0.0f);
    __builtin_amdgcn_s_setprio(1);
#pragma unroll
    for (int nf = 0; nf < 4; ++nf) {
#pragma unroll
      for (int dk = 0; dk < 4; ++dk) {
        bf16x8 bk = *(const bf16x8*)&Kl[cur][(nf * 16 + l16) * 128 +
                                            (((dk * 4 + g) ^ (l16 & 7)) << 3)];
        s4[nf] = __builtin_amdgcn_mfma_f32_16x16x32_bf16(bk, aq[dk], s4[nf], 0, 0, 0);
      }
    }
    __builtin_amdgcn_s_setprio(0);
    float tm = s4[0][0];
#pragma unroll
    for (int nf = 0; nf < 4; ++nf)
#pragma unroll
      for (int r = 0; r < 4; ++r) tm = fmaxf(tm, s4[nf][r]);
    tm = fmaxf(tm, __shfl_xor(tm, 16));
    tm = fmaxf(tm, __shfl_xor(tm, 32));
    // defer-max (T13): keep stale max while growth < 8 (log2 domain)
    const bool nogrow = (tm <= m + 8.0f);
    const float mn = nogrow ? m : tm;
    float ls = 0.f;                  // this lane's partial row-sum
#pragma unroll
    for (int nf = 0; nf < 4; ++nf)
#pragma unroll
      for (int r = 0; r < 4; ++r) {
        float p = exp2f(s4[nf][r] - mn);
        s4[nf][r] = p;
        ls += p;
      }
    // NOTE: no per-tile cross-lane reduce of ls -- lsum stays partial;
    // corr is row-uniform, so partials rescale identically.
    if (__all(nogrow)) {
      lsum += ls;
    } else {
      float corr = exp2f(m - mn);
      m = mn;
      lsum = lsum * corr + ls;
#pragma unroll
      for (int r = 0; r < 4; ++r) {
        float cr = __shfl(corr, 20 * g + r);
#pragma unroll
        for (int df = 0; df < 8; ++df) o[df][r] *= cr;
      }
    }
    // P -> wave-private LDS, packed 4x u16 -> one b64 store per nf
#pragma unroll
    for (int nf = 0; nf < 4; ++nf) {
      unsigned long long pk =
          (unsigned long long)f2bf(s4[nf][0]) |
          ((unsigned long long)f2bf(s4[nf][1]) << 16) |
          ((unsigned long long)f2bf(s4[nf][2]) << 32) |
          ((unsigned long long)f2bf(s4[nf][3]) << 48);
      *(unsigned long long*)&Pl[w][l16][nf * 16 + 4 * g] = pk;
    }
#pragma unroll
    for (int ks = 0; ks < 2; ++ks) {
      bf16x8 ap = *(const bf16x8*)&Pl[w][l16][ks * 32 + g * 8];
      __builtin_amdgcn_s_setprio(1);
#pragma unroll
      for (int df = 0; df < 8; ++df) {
        bf16x8 bv = *(const bf16x8*)&Vl[cur][(df * 16 + l16) * 64 +
                                             (((ks * 4 + g) ^ (l16 & 7)) << 3)];
        o[df] = __builtin_amdgcn_mfma_f32_16x16x32_bf16(ap, bv, o[df], 0, 0, 0);
      }
      __builtin_amdgcn_s_setprio(0);
    }
    __syncthreads();
    cur ^= 1;
  }

  // final cross-lane reduce of the partial lsums (row q = l16)
  lsum += __shfl_xor(lsum, 16);
  lsum += __shfl_xor(lsum, 32);
  const float invq = 1.0f / lsum;
#pragma unroll
  for (int r = 0; r < 4; ++r) {
    float ir = __shfl(invq, 20 * g + r);
#pragma unroll
    for (int df = 0; df < 8; ++df)
      out[(size_t)(q0 + 4 * g + r) * HIDN + h * DHD + df * 16 + l16] =
          f2bf(o[df][r] * ir);
  }
}

// ---------------------------------------------------------------------------
extern "C" void kernel_launch(void* const* d_in, const int* in_sizes, int n_in,
                              void* d_out, int out_size, void* d_ws, size_t ws_size,
                              hipStream_t stream) {
  (void)in_sizes; (void)n_in; (void)out_size; (void)ws_size;
  const float* hs   = (const float*)d_in[0];
  const float* fc   = (const float*)d_in[1];
  const float* fs   = (const float*)d_in[2];
  const float* wqkv = (const float*)d_in[3];
  const float* bqkv = (const float*)d_in[4];
  const float* wnq  = (const float*)d_in[5];
  const float* wnk  = (const float*)d_in[6];
  const float* wout = (const float*)d_in[7];
  const float* bout = (const float*)d_in[8];
  float* out = (float*)d_out;
  char* ws = (char*)d_ws;

  u16* wqkvT = (u16*)(ws);                  // 6144x2048 bf16 (25,165,824 B)
  u16* woutT = (u16*)(ws + 25165824);       // 2048x2048 bf16 ( 8,388,608 B)
  u16* qkv   = (u16*)(ws + 33554432);       // 2048x6144 bf16 (25,165,824 B)
  u16* hsB   = (u16*)(ws + 58720256);       // 2048x2048 bf16
  u16* Qr    = (u16*)(ws + 58720256);       // alias hsB (dead after GEMM1)
  u16* Kr    = (u16*)(ws + 67108864);       // 16x2048x128 bf16
  u16* Vt    = (u16*)(ws + 75497472);       // 16x128x2048 bf16
  u16* attnO = (u16*)(ws + 83886080);       // 2048x2048 bf16

  // 1) fused prep
  prep<<<dim3(6144), 256, 0, stream>>>(wqkv, wout, hs, wqkvT, woutT, hsB);
  // 2) QKV GEMM: single-buffer (3 blocks/CU regime) + by-chunked XCD map
  gemm_sb<<<dim3(768), 256, 0, stream>>>(hsB, wqkvT, bqkv, nullptr, qkv,
                                         2048, 6144, 2048);
  // 3) fused mid
  mid<<<dim3(3072), 256, 0, stream>>>(qkv, fc, fs, wnq, wnk, Qr, Kr, Vt);
  // 4) MFMA flash attention (defer-max + packed P writes + deferred lsum)
  attn_fwd<<<dim3(512), 256, 0, stream>>>(Qr, Kr, Vt, attnO);
  // 5) output projection: double-buffer prefetch (1 block/CU regime)
  gemm_db<<<dim3(256), 256, 0, stream>>>(attnO, woutT, bout, out, nullptr,
                                         2048, 2048, 2048);
}

// Round 28
// 196.653 us; speedup vs baseline: 1.0091x; 1.0091x over previous
//
#include <hip/hip_runtime.h>
#include <math.h>

typedef unsigned short u16;
typedef __bf16 bf16x8 __attribute__((ext_vector_type(8)));
typedef float f32x4 __attribute__((ext_vector_type(4)));
typedef unsigned short u16x8 __attribute__((ext_vector_type(8)));

#define SLEN 2048
#define HIDN 2048
#define NH   16
#define DHD  128

static __device__ __forceinline__ float bf2f(u16 u) {
  unsigned int i = ((unsigned int)u) << 16;
  return __builtin_bit_cast(float, i);
}
static __device__ __forceinline__ u16 f2bf(float f) {
  unsigned int x = __builtin_bit_cast(unsigned int, f);
  unsigned int r = x + 0x7fffu + ((x >> 16) & 1u);
  return (u16)(r >> 16);
}
static __device__ __forceinline__ void gload_lds16(const u16* g, u16* l) {
  __builtin_amdgcn_global_load_lds((const __attribute__((address_space(1))) void*)g,
                                   (__attribute__((address_space(3))) void*)l,
                                   16, 0, 0);
}

// ---------------------------------------------------------------------------
// Fused prep: [0,3072) transpose+cvt w_qkv; [3072,4096) w_out; [4096,6144) hs.
// ---------------------------------------------------------------------------
__global__ __launch_bounds__(256) void prep(const float* __restrict__ wqkv,
                                            const float* __restrict__ wout,
                                            const float* __restrict__ hs,
                                            u16* __restrict__ wqkvT,
                                            u16* __restrict__ woutT,
                                            u16* __restrict__ hsB) {
  const int lin = blockIdx.x;
  const int t = threadIdx.x;
  if (lin >= 4096) {
    int i = ((lin - 4096) * 256 + t) * 8;
    f32x4 a = *(const f32x4*)&hs[i];
    f32x4 b = *(const f32x4*)&hs[i + 4];
    u16x8 v;
#pragma unroll
    for (int j = 0; j < 4; ++j) { v[j] = f2bf(a[j]); v[4 + j] = f2bf(b[j]); }
    *(u16x8*)&hsB[i] = v;
    return;
  }
  const float* in;
  u16* out;
  int istride, ostride, bx, by;
  if (lin < 3072) {
    in = wqkv; out = wqkvT; istride = 6144; ostride = 2048;
    bx = lin & 31; by = lin >> 5;
  } else {
    in = wout; out = woutT; istride = 2048; ostride = 2048;
    int idx = lin - 3072;
    bx = idx & 31; by = idx >> 5;
  }
  __shared__ float tl[64][65];
  const int r0 = bx * 64, c0 = by * 64;
#pragma unroll
  for (int it = 0; it < 4; ++it) {
    int row = it * 16 + (t >> 4);
    int col = (t & 15) * 4;
    f32x4 v = *(const f32x4*)&in[(size_t)(r0 + row) * istride + c0 + col];
    tl[row][col] = v[0]; tl[row][col + 1] = v[1];
    tl[row][col + 2] = v[2]; tl[row][col + 3] = v[3];
  }
  __syncthreads();
#pragma unroll
  for (int it = 0; it < 2; ++it) {
    int orow = it * 32 + (t >> 3);
    int ocol = (t & 7) * 8;
    u16x8 v;
#pragma unroll
    for (int j = 0; j < 8; ++j) v[j] = f2bf(tl[ocol + j][orow]);
    *(u16x8*)&out[(size_t)(c0 + orow) * ostride + r0 + ocol] = v;
  }
}

// ---------------------------------------------------------------------------
// XCD by-chunked block mapping (B-panels L2-resident per XCD).
// ---------------------------------------------------------------------------
static __device__ __forceinline__ void xcd_map(int lin, int N, int* pbx, int* pby) {
  const int nby = N >> 7;
  const int cby = nby >> 3;
  const int xcd = lin & 7, idx = lin >> 3;
  *pby = xcd * cby + (idx % cby);
  *pbx = idx / cby;
}

// ---------------------------------------------------------------------------
// MFMA GEMM single-buffer (3-blocks/CU regime).  C = A * BT^T + bias.
// ---------------------------------------------------------------------------
__global__ __launch_bounds__(256) void gemm_sb(const u16* __restrict__ A,
                                               const u16* __restrict__ BT,
                                               const float* __restrict__ bias,
                                               float* Cf, u16* Cb,
                                               int M, int N, int K) {
  int bx, by;
  xcd_map(blockIdx.x, N, &bx, &by);

  __shared__ u16 lA[128 * 64];
  __shared__ u16 lB[128 * 64];
  const int t = threadIdx.x;
  const int lane = t & 63, w = t >> 6;
  const int g = lane >> 4, l16 = lane & 15;
  const int wr = w >> 1, wc = w & 1;
  const u16* Ab = A + (size_t)bx * 128 * K;
  const u16* Bb = BT + (size_t)by * 128 * K;

  f32x4 acc[4][4];
#pragma unroll
  for (int mi = 0; mi < 4; ++mi)
#pragma unroll
    for (int ni = 0; ni < 4; ++ni) acc[mi][ni] = (f32x4)(0.0f);

  for (int k0 = 0; k0 < K; k0 += 64) {
    __syncthreads();
#pragma unroll
    for (int i = 0; i < 4; ++i) {
      int e = t * 8 + i * 2048;
      int row = e >> 6;
      int col16 = (e & 63) >> 3;
      int scol = (col16 ^ (row & 7)) * 8;
      gload_lds16(Ab + (size_t)row * K + k0 + scol, &lA[e]);
      gload_lds16(Bb + (size_t)row * K + k0 + scol, &lB[e]);
    }
    __syncthreads();
#pragma unroll
    for (int kk = 0; kk < 2; ++kk) {
      bf16x8 af[4], bfr[4];
#pragma unroll
      for (int mi = 0; mi < 4; ++mi) {
        int row = wr * 64 + mi * 16 + l16;
        af[mi] = *(const bf16x8*)&lA[row * 64 + (((4 * kk + g) ^ (l16 & 7)) << 3)];
      }
#pragma unroll
      for (int ni = 0; ni < 4; ++ni) {
        int row = wc * 64 + ni * 16 + l16;
        bfr[ni] = *(const bf16x8*)&lB[row * 64 + (((4 * kk + g) ^ (l16 & 7)) << 3)];
      }
#pragma unroll
      for (int mi = 0; mi < 4; ++mi)
#pragma unroll
        for (int ni = 0; ni < 4; ++ni)
          acc[mi][ni] = __builtin_amdgcn_mfma_f32_16x16x32_bf16(af[mi], bfr[ni],
                                                                acc[mi][ni], 0, 0, 0);
    }
  }

#pragma unroll
  for (int ni = 0; ni < 4; ++ni) {
    int n = by * 128 + wc * 64 + ni * 16 + l16;
    float bv = bias[n];
#pragma unroll
    for (int mi = 0; mi < 4; ++mi) {
      int m = bx * 128 + wr * 64 + mi * 16 + 4 * g;
#pragma unroll
      for (int r = 0; r < 4; ++r) {
        float v = acc[mi][ni][r] + bv;
        if (Cf) Cf[(size_t)(m + r) * N + n] = v;
        else    Cb[(size_t)(m + r) * N + n] = f2bf(v);
      }
    }
  }
}

// ---------------------------------------------------------------------------
// MFMA GEMM double-buffer 2-phase prefetch (1-block/CU regime; ~2x in r20).
// ---------------------------------------------------------------------------
__global__ __launch_bounds__(256) void gemm_db(const u16* __restrict__ A,
                                               const u16* __restrict__ BT,
                                               const float* __restrict__ bias,
                                               float* Cf, u16* Cb,
                                               int M, int N, int K) {
  int bx, by;
  xcd_map(blockIdx.x, N, &bx, &by);

  __shared__ u16 lA[2][128 * 64];
  __shared__ u16 lB[2][128 * 64];
  const int t = threadIdx.x;
  const int lane = t & 63, w = t >> 6;
  const int g = lane >> 4, l16 = lane & 15;
  const int wr = w >> 1, wc = w & 1;
  const u16* Ab = A + (size_t)bx * 128 * K;
  const u16* Bb = BT + (size_t)by * 128 * K;

  f32x4 acc[4][4];
#pragma unroll
  for (int mi = 0; mi < 4; ++mi)
#pragma unroll
    for (int ni = 0; ni < 4; ++ni) acc[mi][ni] = (f32x4)(0.0f);

#pragma unroll
  for (int i = 0; i < 4; ++i) {
    int e = t * 8 + i * 2048;
    int row = e >> 6;
    int col16 = (e & 63) >> 3;
    int scol = (col16 ^ (row & 7)) * 8;
    gload_lds16(Ab + (size_t)row * K + scol, &lA[0][e]);
    gload_lds16(Bb + (size_t)row * K + scol, &lB[0][e]);
  }
  __syncthreads();

  const int nk = K >> 6;
  int cur = 0;
  for (int kt = 0; kt < nk; ++kt) {
    if (kt + 1 < nk) {
      const int k1 = (kt + 1) << 6;
#pragma unroll
      for (int i = 0; i < 4; ++i) {
        int e = t * 8 + i * 2048;
        int row = e >> 6;
        int col16 = (e & 63) >> 3;
        int scol = (col16 ^ (row & 7)) * 8;
        gload_lds16(Ab + (size_t)row * K + k1 + scol, &lA[cur ^ 1][e]);
        gload_lds16(Bb + (size_t)row * K + k1 + scol, &lB[cur ^ 1][e]);
      }
    }
#pragma unroll
    for (int kk = 0; kk < 2; ++kk) {
      bf16x8 af[4], bfr[4];
#pragma unroll
      for (int mi = 0; mi < 4; ++mi) {
        int row = wr * 64 + mi * 16 + l16;
        af[mi] = *(const bf16x8*)&lA[cur][row * 64 + (((4 * kk + g) ^ (l16 & 7)) << 3)];
      }
#pragma unroll
      for (int ni = 0; ni < 4; ++ni) {
        int row = wc * 64 + ni * 16 + l16;
        bfr[ni] = *(const bf16x8*)&lB[cur][row * 64 + (((4 * kk + g) ^ (l16 & 7)) << 3)];
      }
#pragma unroll
      for (int mi = 0; mi < 4; ++mi)
#pragma unroll
        for (int ni = 0; ni < 4; ++ni)
          acc[mi][ni] = __builtin_amdgcn_mfma_f32_16x16x32_bf16(af[mi], bfr[ni],
                                                                acc[mi][ni], 0, 0, 0);
    }
    __syncthreads();
    cur ^= 1;
  }

#pragma unroll
  for (int ni = 0; ni < 4; ++ni) {
    int n = by * 128 + wc * 64 + ni * 16 + l16;
    float bv = bias[n];
#pragma unroll
    for (int mi = 0; mi < 4; ++mi) {
      int m = bx * 128 + wr * 64 + mi * 16 + 4 * g;
#pragma unroll
      for (int r = 0; r < 4; ++r) {
        float v = acc[mi][ni][r] + bv;
        if (Cf) Cf[(size_t)(m + r) * N + n] = v;
        else    Cb[(size_t)(m + r) * N + n] = f2bf(v);
      }
    }
  }
}

// ---------------------------------------------------------------------------
// Fused mid: [0,2048) rms_rope; [2048,3072) V transpose -> Vt[h][d][s].
// ---------------------------------------------------------------------------
__global__ __launch_bounds__(256) void mid(const u16* __restrict__ qkv,
                                           const float* __restrict__ fcos,
                                           const float* __restrict__ fsin,
                                           const float* __restrict__ wq,
                                           const float* __restrict__ wk,
                                           u16* __restrict__ Qr,
                                           u16* __restrict__ Kr,
                                           u16* __restrict__ Vt) {
  const int lin = blockIdx.x;
  const int t = threadIdx.x;

  if (lin >= 2048) {
    __shared__ u16 tl[64][72];
    int idx = lin - 2048;
    int bx = idx & 31;
    int byy = (idx >> 5) & 1;
    int z = idx >> 6;
    const u16* in = qkv + 4096 + (size_t)z * 128;
    u16* out = Vt + (size_t)z * 262144;
    const int r0 = bx * 64, c0 = byy * 64;
#pragma unroll
    for (int it = 0; it < 2; ++it) {
      int row = it * 32 + (t >> 3);
      int col = (t & 7) * 8;
      *(u16x8*)&tl[row][col] =
          *(const u16x8*)&in[(size_t)(r0 + row) * 6144 + c0 + col];
    }
    __syncthreads();
#pragma unroll
    for (int it = 0; it < 2; ++it) {
      int orow = it * 32 + (t >> 3);
      int ocol = (t & 7) * 8;
      u16x8 v;
#pragma unroll
      for (int j = 0; j < 8; ++j) v[j] = tl[ocol + j][orow];
      *(u16x8*)&out[(size_t)(c0 + orow) * 2048 + r0 + ocol] = v;
    }
    return;
  }

  const int s = lin;
  const int lane = t & 63, w = t >> 6;
  __shared__ float red[2][4];
  const u16* row = qkv + (size_t)s * (3 * HIDN);

  u16x8 xq = *(const u16x8*)&row[t * 8];
  u16x8 xk = *(const u16x8*)&row[HIDN + t * 8];
  float fq[8], fk[8];
  float ssq = 0.f, ssk = 0.f;
#pragma unroll
  for (int j = 0; j < 8; ++j) {
    fq[j] = bf2f(xq[j]); ssq += fq[j] * fq[j];
    fk[j] = bf2f(xk[j]); ssk += fk[j] * fk[j];
  }
#pragma unroll
  for (int off = 32; off >= 1; off >>= 1) {
    ssq += __shfl_xor(ssq, off);
    ssk += __shfl_xor(ssk, off);
  }
  if (lane == 0) { red[0][w] = ssq; red[1][w] = ssk; }
  __syncthreads();
  float sq = red[0][0] + red[0][1] + red[0][2] + red[0][3];
  float sk = red[1][0] + red[1][1] + red[1][2] + red[1][3];
  float rq = rsqrtf(sq / (float)HIDN + 1e-6f);
  float rk = rsqrtf(sk / (float)HIDN + 1e-6f);

  f32x4 wq0 = *(const f32x4*)&wq[t * 8];
  f32x4 wq1 = *(const f32x4*)&wq[t * 8 + 4];
  f32x4 wk0 = *(const f32x4*)&wk[t * 8];
  f32x4 wk1 = *(const f32x4*)&wk[t * 8 + 4];
  float wqa[8] = {wq0[0], wq0[1], wq0[2], wq0[3], wq1[0], wq1[1], wq1[2], wq1[3]};
  float wka[8] = {wk0[0], wk0[1], wk0[2], wk0[3], wk1[0], wk1[1], wk1[2], wk1[3]};
  const int c0 = t * 8;
  const int h = c0 >> 7;
  const int d0 = c0 & 127;
  const int i0 = d0 >> 1;
  const float* cp = fcos + (size_t)s * (DHD / 2) + i0;
  const float* sp = fsin + (size_t)s * (DHD / 2) + i0;
  const float qscale = 0.12751744925f;  // log2(e)/sqrt(128)

  u16x8 oq, ok;
#pragma unroll
  for (int p = 0; p < 4; ++p) {
    float c = cp[p], sn = sp[p];
    float q1 = fq[2 * p] * rq * wqa[2 * p];
    float q2 = fq[2 * p + 1] * rq * wqa[2 * p + 1];
    float k1 = fk[2 * p] * rk * wka[2 * p];
    float k2 = fk[2 * p + 1] * rk * wka[2 * p + 1];
    oq[2 * p]     = f2bf((q1 * c - q2 * sn) * qscale);
    oq[2 * p + 1] = f2bf((q1 * sn + q2 * c) * qscale);
    ok[2 * p]     = f2bf(k1 * c - k2 * sn);
    ok[2 * p + 1] = f2bf(k1 * sn + k2 * c);
  }
  size_t o = (size_t)h * SLEN * DHD + (size_t)s * DHD + d0;
  *(u16x8*)&Qr[o] = oq;
  *(u16x8*)&Kr[o] = ok;
}

// ---------------------------------------------------------------------------
// MFMA flash attention (r27 + lazy tm reduce):
// K AND V LDS-staged (global_load_lds w16, XOR-swizzled, double-buffered,
// shared by 4 waves) + XCD-aware block mapping.  Swapped-operand QK^T ->
// lane-local softmax in exp2 domain.  Defer-max THR=8 (T13); packed b64 P
// writes; deferred lsum (per-lane partial, one final reduce).
// NEW: the per-tile tm cross-lane reduce is LAZY -- the defer-max test runs
// on each lane's LOCAL max first; only if some lane exceeds m+8 (rare) do we
// reduce tm across lanes and rescale.  Fast path: 0 shfls/tile.
// ---------------------------------------------------------------------------
__global__ __launch_bounds__(256) void attn_fwd(const u16* __restrict__ Qr,
                                                const u16* __restrict__ Kr,
                                                const u16* __restrict__ Vt,
                                                u16* __restrict__ out) {
  const int lin = blockIdx.x;
  const int xcd = lin & 7, idx = lin >> 3;
  const int h = xcd + ((idx >> 5) << 3);
  const int qb = idx & 31;
  const int t = threadIdx.x;
  const int lane = t & 63, w = t >> 6;
  const int g = lane >> 4, l16 = lane & 15;
  const int q0 = qb * 64 + w * 16;
  const u16* Qh = Qr + (size_t)h * SLEN * DHD;
  const u16* Kh = Kr + (size_t)h * SLEN * DHD;
  const u16* Vh = Vt + (size_t)h * DHD * SLEN;

  __shared__ u16 Kl[2][64 * 128];
  __shared__ u16 Vl[2][128 * 64];
  __shared__ u16 Pl[4][16][72];

  bf16x8 aq[4];
#pragma unroll
  for (int dk = 0; dk < 4; ++dk)
    aq[dk] = *(const bf16x8*)&Qh[(size_t)(q0 + l16) * DHD + dk * 32 + g * 8];

  f32x4 o[8];
#pragma unroll
  for (int df = 0; df < 8; ++df) o[df] = (f32x4)(0.0f);
  float m = -INFINITY, lsum = 0.f;   // lsum = per-lane PARTIAL (16 kv values)

#pragma unroll
  for (int i = 0; i < 4; ++i) {
    int e = t * 8 + i * 2048;
    int kr = e >> 7, kc = (e & 127) >> 3;
    gload_lds16(Kh + (size_t)kr * DHD + ((kc ^ (kr & 7)) << 3), &Kl[0][e]);
    int vr = e >> 6, vc = (e & 63) >> 3;
    gload_lds16(Vh + (size_t)vr * SLEN + ((vc ^ (vr & 7)) << 3), &Vl[0][e]);
  }
  __syncthreads();

  int cur = 0;
  for (int kt = 0; kt < SLEN / 64; ++kt) {
    if (kt + 1 < SLEN / 64) {
      const int kv1 = (kt + 1) * 64;
#pragma unroll
      for (int i = 0; i < 4; ++i) {
        int e = t * 8 + i * 2048;
        int kr = e >> 7, kc = (e & 127) >> 3;
        gload_lds16(Kh + (size_t)(kv1 + kr) * DHD + ((kc ^ (kr & 7)) << 3),
                    &Kl[cur ^ 1][e]);
        int vr = e >> 6, vc = (e & 63) >> 3;
        gload_lds16(Vh + (size_t)vr * SLEN + kv1 + ((vc ^ (vr & 7)) << 3),
                    &Vl[cur ^ 1][e]);
      }
    }

    f32x4 s4[4];
#pragma unroll
    for (int nf = 0; nf < 4; ++nf) s4[nf] = (f32x4)(0.0f);
    __builtin_amdgcn_s_setprio(1);
#pragma unroll
    for (int nf = 0; nf < 4; ++nf) {
#pragma unroll
      for (int dk = 0; dk < 4; ++dk) {
        bf16x8 bk = *(const bf16x8*)&Kl[cur][(nf * 16 + l16) * 128 +
                                            (((dk * 4 + g) ^ (l16 & 7)) << 3)];
        s4[nf] = __builtin_amdgcn_mfma_f32_16x16x32_bf16(bk, aq[dk], s4[nf], 0, 0, 0);
      }
    }
    __builtin_amdgcn_s_setprio(0);
    // per-lane LOCAL max of this lane's 16 scores
    float tml = s4[0][0];
#pragma unroll
    for (int nf = 0; nf < 4; ++nf)
#pragma unroll
      for (int r = 0; r < 4; ++r) tml = fmaxf(tml, s4[nf][r]);

    if (__all(tml <= m + 8.0f)) {
      // FAST PATH (defer-max, T13): row max grew < 8 -> keep stale m.
      // No cross-lane ops at all.
      float ls = 0.f;
#pragma unroll
      for (int nf = 0; nf < 4; ++nf)
#pragma unroll
        for (int r = 0; r < 4; ++r) {
          float p = exp2f(s4[nf][r] - m);
          s4[nf][r] = p;
          ls += p;
        }
      lsum += ls;
    } else {
      // SLOW PATH: reduce tm across the row, rescale state.
      float tm = fmaxf(tml, __shfl_xor(tml, 16));
      tm = fmaxf(tm, __shfl_xor(tm, 32));
      const float mn = fmaxf(m, tm);
      const float corr = exp2f(m - mn);
      float ls = 0.f;
#pragma unroll
      for (int nf = 0; nf < 4; ++nf)
#pragma unroll
        for (int r = 0; r < 4; ++r) {
          float p = exp2f(s4[nf][r] - mn);
          s4[nf][r] = p;
          ls += p;
        }
      m = mn;
      lsum = lsum * corr + ls;
#pragma unroll
      for (int r = 0; r < 4; ++r) {
        float cr = __shfl(corr, 20 * g + r);
#pragma unroll
        for (int df = 0; df < 8; ++df) o[df][r] *= cr;
      }
    }
    // P -> wave-private LDS, packed 4x u16 -> one b64 store per nf
#pragma unroll
    for (int nf = 0; nf < 4; ++nf) {
      unsigned long long pk =
          (unsigned long long)f2bf(s4[nf][0]) |
          ((unsigned long long)f2bf(s4[nf][1]) << 16) |
          ((unsigned long long)f2bf(s4[nf][2]) << 32) |
          ((unsigned long long)f2bf(s4[nf][3]) << 48);
      *(unsigned long long*)&Pl[w][l16][nf * 16 + 4 * g] = pk;
    }
#pragma unroll
    for (int ks = 0; ks < 2; ++ks) {
      bf16x8 ap = *(const bf16x8*)&Pl[w][l16][ks * 32 + g * 8];
      __builtin_amdgcn_s_setprio(1);
#pragma unroll
      for (int df = 0; df < 8; ++df) {
        bf16x8 bv = *(const bf16x8*)&Vl[cur][(df * 16 + l16) * 64 +
                                             (((ks * 4 + g) ^ (l16 & 7)) << 3)];
        o[df] = __builtin_amdgcn_mfma_f32_16x16x32_bf16(ap, bv, o[df], 0, 0, 0);
      }
      __builtin_amdgcn_s_setprio(0);
    }
    __syncthreads();
    cur ^= 1;
  }

  // final cross-lane reduce of the partial lsums (row q = l16)
  lsum += __shfl_xor(lsum, 16);
  lsum += __shfl_xor(lsum, 32);
  const float invq = 1.0f / lsum;
#pragma unroll
  for (int r = 0; r < 4; ++r) {
    float ir = __shfl(invq, 20 * g + r);
#pragma unroll
    for (int df = 0; df < 8; ++df)
      out[(size_t)(q0 + 4 * g + r) * HIDN + h * DHD + df * 16 + l16] =
          f2bf(o[df][r] * ir);
  }
}

// ---------------------------------------------------------------------------
extern "C" void kernel_launch(void* const* d_in, const int* in_sizes, int n_in,
                              void* d_out, int out_size, void* d_ws, size_t ws_size,
                              hipStream_t stream) {
  (void)in_sizes; (void)n_in; (void)out_size; (void)ws_size;
  const float* hs   = (const float*)d_in[0];
  const float* fc   = (const float*)d_in[1];
  const float* fs   = (const float*)d_in[2];
  const float* wqkv = (const float*)d_in[3];
  const float* bqkv = (const float*)d_in[4];
  const float* wnq  = (const float*)d_in[5];
  const float* wnk  = (const float*)d_in[6];
  const float* wout = (const float*)d_in[7];
  const float* bout = (const float*)d_in[8];
  float* out = (float*)d_out;
  char* ws = (char*)d_ws;

  u16* wqkvT = (u16*)(ws);                  // 6144x2048 bf16 (25,165,824 B)
  u16* woutT = (u16*)(ws + 25165824);       // 2048x2048 bf16 ( 8,388,608 B)
  u16* qkv   = (u16*)(ws + 33554432);       // 2048x6144 bf16 (25,165,824 B)
  u16* hsB   = (u16*)(ws + 58720256);       // 2048x2048 bf16
  u16* Qr    = (u16*)(ws + 58720256);       // alias hsB (dead after GEMM1)
  u16* Kr    = (u16*)(ws + 67108864);       // 16x2048x128 bf16
  u16* Vt    = (u16*)(ws + 75497472);       // 16x128x2048 bf16
  u16* attnO = (u16*)(ws + 83886080);       // 2048x2048 bf16

  // 1) fused prep
  prep<<<dim3(6144), 256, 0, stream>>>(wqkv, wout, hs, wqkvT, woutT, hsB);
  // 2) QKV GEMM: single-buffer (3 blocks/CU regime) + by-chunked XCD map
  gemm_sb<<<dim3(768), 256, 0, stream>>>(hsB, wqkvT, bqkv, nullptr, qkv,
                                         2048, 6144, 2048);
  // 3) fused mid
  mid<<<dim3(3072), 256, 0, stream>>>(qkv, fc, fs, wnq, wnk, Qr, Kr, Vt);
  // 4) MFMA flash attention (defer-max + packed P + deferred lsum + lazy tm)
  attn_fwd<<<dim3(512), 256, 0, stream>>>(Qr, Kr, Vt, attnO);
  // 5) output projection: double-buffer prefetch (1 block/CU regime)
  gemm_db<<<dim3(256), 256, 0, stream>>>(attnO, woutT, bout, out, nullptr,
                                         2048, 2048, 2048);
}

// Round 29
// 196.416 us; speedup vs baseline: 1.0103x; 1.0012x over previous
//
#include <hip/hip_runtime.h>
#include <math.h>

typedef unsigned short u16;
typedef __bf16 bf16x8 __attribute__((ext_vector_type(8)));
typedef float f32x4 __attribute__((ext_vector_type(4)));
typedef unsigned short u16x8 __attribute__((ext_vector_type(8)));

#define SLEN 2048
#define HIDN 2048
#define NH   16
#define DHD  128

static __device__ __forceinline__ float bf2f(u16 u) {
  unsigned int i = ((unsigned int)u) << 16;
  return __builtin_bit_cast(float, i);
}
static __device__ __forceinline__ u16 f2bf(float f) {
  unsigned int x = __builtin_bit_cast(unsigned int, f);
  unsigned int r = x + 0x7fffu + ((x >> 16) & 1u);
  return (u16)(r >> 16);
}
static __device__ __forceinline__ void gload_lds16(const u16* g, u16* l) {
  __builtin_amdgcn_global_load_lds((const __attribute__((address_space(1))) void*)g,
                                   (__attribute__((address_space(3))) void*)l,
                                   16, 0, 0);
}

// ---------------------------------------------------------------------------
// Fused prep: [0,3072) transpose+cvt w_qkv; [3072,4096) w_out; [4096,6144) hs.
// ---------------------------------------------------------------------------
__global__ __launch_bounds__(256) void prep(const float* __restrict__ wqkv,
                                            const float* __restrict__ wout,
                                            const float* __restrict__ hs,
                                            u16* __restrict__ wqkvT,
                                            u16* __restrict__ woutT,
                                            u16* __restrict__ hsB) {
  const int lin = blockIdx.x;
  const int t = threadIdx.x;
  if (lin >= 4096) {
    int i = ((lin - 4096) * 256 + t) * 8;
    f32x4 a = *(const f32x4*)&hs[i];
    f32x4 b = *(const f32x4*)&hs[i + 4];
    u16x8 v;
#pragma unroll
    for (int j = 0; j < 4; ++j) { v[j] = f2bf(a[j]); v[4 + j] = f2bf(b[j]); }
    *(u16x8*)&hsB[i] = v;
    return;
  }
  const float* in;
  u16* out;
  int istride, ostride, bx, by;
  if (lin < 3072) {
    in = wqkv; out = wqkvT; istride = 6144; ostride = 2048;
    bx = lin & 31; by = lin >> 5;
  } else {
    in = wout; out = woutT; istride = 2048; ostride = 2048;
    int idx = lin - 3072;
    bx = idx & 31; by = idx >> 5;
  }
  __shared__ float tl[64][65];
  const int r0 = bx * 64, c0 = by * 64;
#pragma unroll
  for (int it = 0; it < 4; ++it) {
    int row = it * 16 + (t >> 4);
    int col = (t & 15) * 4;
    f32x4 v = *(const f32x4*)&in[(size_t)(r0 + row) * istride + c0 + col];
    tl[row][col] = v[0]; tl[row][col + 1] = v[1];
    tl[row][col + 2] = v[2]; tl[row][col + 3] = v[3];
  }
  __syncthreads();
#pragma unroll
  for (int it = 0; it < 2; ++it) {
    int orow = it * 32 + (t >> 3);
    int ocol = (t & 7) * 8;
    u16x8 v;
#pragma unroll
    for (int j = 0; j < 8; ++j) v[j] = f2bf(tl[ocol + j][orow]);
    *(u16x8*)&out[(size_t)(c0 + orow) * ostride + r0 + ocol] = v;
  }
}

// ---------------------------------------------------------------------------
// XCD by-chunked block mapping (B-panels L2-resident per XCD).
// ---------------------------------------------------------------------------
static __device__ __forceinline__ void xcd_map(int lin, int N, int* pbx, int* pby) {
  const int nby = N >> 7;
  const int cby = nby >> 3;
  const int xcd = lin & 7, idx = lin >> 3;
  *pby = xcd * cby + (idx % cby);
  *pbx = idx / cby;
}

// ---------------------------------------------------------------------------
// MFMA GEMM single-buffer (3-blocks/CU regime).  C = A * BT^T + bias.
// ---------------------------------------------------------------------------
__global__ __launch_bounds__(256) void gemm_sb(const u16* __restrict__ A,
                                               const u16* __restrict__ BT,
                                               const float* __restrict__ bias,
                                               float* Cf, u16* Cb,
                                               int M, int N, int K) {
  int bx, by;
  xcd_map(blockIdx.x, N, &bx, &by);

  __shared__ u16 lA[128 * 64];
  __shared__ u16 lB[128 * 64];
  const int t = threadIdx.x;
  const int lane = t & 63, w = t >> 6;
  const int g = lane >> 4, l16 = lane & 15;
  const int wr = w >> 1, wc = w & 1;
  const u16* Ab = A + (size_t)bx * 128 * K;
  const u16* Bb = BT + (size_t)by * 128 * K;

  f32x4 acc[4][4];
#pragma unroll
  for (int mi = 0; mi < 4; ++mi)
#pragma unroll
    for (int ni = 0; ni < 4; ++ni) acc[mi][ni] = (f32x4)(0.0f);

  for (int k0 = 0; k0 < K; k0 += 64) {
    __syncthreads();
#pragma unroll
    for (int i = 0; i < 4; ++i) {
      int e = t * 8 + i * 2048;
      int row = e >> 6;
      int col16 = (e & 63) >> 3;
      int scol = (col16 ^ (row & 7)) * 8;
      gload_lds16(Ab + (size_t)row * K + k0 + scol, &lA[e]);
      gload_lds16(Bb + (size_t)row * K + k0 + scol, &lB[e]);
    }
    __syncthreads();
#pragma unroll
    for (int kk = 0; kk < 2; ++kk) {
      bf16x8 af[4], bfr[4];
#pragma unroll
      for (int mi = 0; mi < 4; ++mi) {
        int row = wr * 64 + mi * 16 + l16;
        af[mi] = *(const bf16x8*)&lA[row * 64 + (((4 * kk + g) ^ (l16 & 7)) << 3)];
      }
#pragma unroll
      for (int ni = 0; ni < 4; ++ni) {
        int row = wc * 64 + ni * 16 + l16;
        bfr[ni] = *(const bf16x8*)&lB[row * 64 + (((4 * kk + g) ^ (l16 & 7)) << 3)];
      }
#pragma unroll
      for (int mi = 0; mi < 4; ++mi)
#pragma unroll
        for (int ni = 0; ni < 4; ++ni)
          acc[mi][ni] = __builtin_amdgcn_mfma_f32_16x16x32_bf16(af[mi], bfr[ni],
                                                                acc[mi][ni], 0, 0, 0);
    }
  }

#pragma unroll
  for (int ni = 0; ni < 4; ++ni) {
    int n = by * 128 + wc * 64 + ni * 16 + l16;
    float bv = bias[n];
#pragma unroll
    for (int mi = 0; mi < 4; ++mi) {
      int m = bx * 128 + wr * 64 + mi * 16 + 4 * g;
#pragma unroll
      for (int r = 0; r < 4; ++r) {
        float v = acc[mi][ni][r] + bv;
        if (Cf) Cf[(size_t)(m + r) * N + n] = v;
        else    Cb[(size_t)(m + r) * N + n] = f2bf(v);
      }
    }
  }
}

// ---------------------------------------------------------------------------
// MFMA GEMM double-buffer 2-phase prefetch (1-block/CU regime; ~2x in r20).
// ---------------------------------------------------------------------------
__global__ __launch_bounds__(256) void gemm_db(const u16* __restrict__ A,
                                               const u16* __restrict__ BT,
                                               const float* __restrict__ bias,
                                               float* Cf, u16* Cb,
                                               int M, int N, int K) {
  int bx, by;
  xcd_map(blockIdx.x, N, &bx, &by);

  __shared__ u16 lA[2][128 * 64];
  __shared__ u16 lB[2][128 * 64];
  const int t = threadIdx.x;
  const int lane = t & 63, w = t >> 6;
  const int g = lane >> 4, l16 = lane & 15;
  const int wr = w >> 1, wc = w & 1;
  const u16* Ab = A + (size_t)bx * 128 * K;
  const u16* Bb = BT + (size_t)by * 128 * K;

  f32x4 acc[4][4];
#pragma unroll
  for (int mi = 0; mi < 4; ++mi)
#pragma unroll
    for (int ni = 0; ni < 4; ++ni) acc[mi][ni] = (f32x4)(0.0f);

#pragma unroll
  for (int i = 0; i < 4; ++i) {
    int e = t * 8 + i * 2048;
    int row = e >> 6;
    int col16 = (e & 63) >> 3;
    int scol = (col16 ^ (row & 7)) * 8;
    gload_lds16(Ab + (size_t)row * K + scol, &lA[0][e]);
    gload_lds16(Bb + (size_t)row * K + scol, &lB[0][e]);
  }
  __syncthreads();

  const int nk = K >> 6;
  int cur = 0;
  for (int kt = 0; kt < nk; ++kt) {
    if (kt + 1 < nk) {
      const int k1 = (kt + 1) << 6;
#pragma unroll
      for (int i = 0; i < 4; ++i) {
        int e = t * 8 + i * 2048;
        int row = e >> 6;
        int col16 = (e & 63) >> 3;
        int scol = (col16 ^ (row & 7)) * 8;
        gload_lds16(Ab + (size_t)row * K + k1 + scol, &lA[cur ^ 1][e]);
        gload_lds16(Bb + (size_t)row * K + k1 + scol, &lB[cur ^ 1][e]);
      }
    }
#pragma unroll
    for (int kk = 0; kk < 2; ++kk) {
      bf16x8 af[4], bfr[4];
#pragma unroll
      for (int mi = 0; mi < 4; ++mi) {
        int row = wr * 64 + mi * 16 + l16;
        af[mi] = *(const bf16x8*)&lA[cur][row * 64 + (((4 * kk + g) ^ (l16 & 7)) << 3)];
      }
#pragma unroll
      for (int ni = 0; ni < 4; ++ni) {
        int row = wc * 64 + ni * 16 + l16;
        bfr[ni] = *(const bf16x8*)&lB[cur][row * 64 + (((4 * kk + g) ^ (l16 & 7)) << 3)];
      }
#pragma unroll
      for (int mi = 0; mi < 4; ++mi)
#pragma unroll
        for (int ni = 0; ni < 4; ++ni)
          acc[mi][ni] = __builtin_amdgcn_mfma_f32_16x16x32_bf16(af[mi], bfr[ni],
                                                                acc[mi][ni], 0, 0, 0);
    }
    __syncthreads();
    cur ^= 1;
  }

#pragma unroll
  for (int ni = 0; ni < 4; ++ni) {
    int n = by * 128 + wc * 64 + ni * 16 + l16;
    float bv = bias[n];
#pragma unroll
    for (int mi = 0; mi < 4; ++mi) {
      int m = bx * 128 + wr * 64 + mi * 16 + 4 * g;
#pragma unroll
      for (int r = 0; r < 4; ++r) {
        float v = acc[mi][ni][r] + bv;
        if (Cf) Cf[(size_t)(m + r) * N + n] = v;
        else    Cb[(size_t)(m + r) * N + n] = f2bf(v);
      }
    }
  }
}

// ---------------------------------------------------------------------------
// Fused mid: [0,2048) rms_rope; [2048,3072) V transpose -> Vt[h][d][s].
// ---------------------------------------------------------------------------
__global__ __launch_bounds__(256) void mid(const u16* __restrict__ qkv,
                                           const float* __restrict__ fcos,
                                           const float* __restrict__ fsin,
                                           const float* __restrict__ wq,
                                           const float* __restrict__ wk,
                                           u16* __restrict__ Qr,
                                           u16* __restrict__ Kr,
                                           u16* __restrict__ Vt) {
  const int lin = blockIdx.x;
  const int t = threadIdx.x;

  if (lin >= 2048) {
    __shared__ u16 tl[64][72];
    int idx = lin - 2048;
    int bx = idx & 31;
    int byy = (idx >> 5) & 1;
    int z = idx >> 6;
    const u16* in = qkv + 4096 + (size_t)z * 128;
    u16* out = Vt + (size_t)z * 262144;
    const int r0 = bx * 64, c0 = byy * 64;
#pragma unroll
    for (int it = 0; it < 2; ++it) {
      int row = it * 32 + (t >> 3);
      int col = (t & 7) * 8;
      *(u16x8*)&tl[row][col] =
          *(const u16x8*)&in[(size_t)(r0 + row) * 6144 + c0 + col];
    }
    __syncthreads();
#pragma unroll
    for (int it = 0; it < 2; ++it) {
      int orow = it * 32 + (t >> 3);
      int ocol = (t & 7) * 8;
      u16x8 v;
#pragma unroll
      for (int j = 0; j < 8; ++j) v[j] = tl[ocol + j][orow];
      *(u16x8*)&out[(size_t)(c0 + orow) * 2048 + r0 + ocol] = v;
    }
    return;
  }

  const int s = lin;
  const int lane = t & 63, w = t >> 6;
  __shared__ float red[2][4];
  const u16* row = qkv + (size_t)s * (3 * HIDN);

  u16x8 xq = *(const u16x8*)&row[t * 8];
  u16x8 xk = *(const u16x8*)&row[HIDN + t * 8];
  float fq[8], fk[8];
  float ssq = 0.f, ssk = 0.f;
#pragma unroll
  for (int j = 0; j < 8; ++j) {
    fq[j] = bf2f(xq[j]); ssq += fq[j] * fq[j];
    fk[j] = bf2f(xk[j]); ssk += fk[j] * fk[j];
  }
#pragma unroll
  for (int off = 32; off >= 1; off >>= 1) {
    ssq += __shfl_xor(ssq, off);
    ssk += __shfl_xor(ssk, off);
  }
  if (lane == 0) { red[0][w] = ssq; red[1][w] = ssk; }
  __syncthreads();
  float sq = red[0][0] + red[0][1] + red[0][2] + red[0][3];
  float sk = red[1][0] + red[1][1] + red[1][2] + red[1][3];
  float rq = rsqrtf(sq / (float)HIDN + 1e-6f);
  float rk = rsqrtf(sk / (float)HIDN + 1e-6f);

  f32x4 wq0 = *(const f32x4*)&wq[t * 8];
  f32x4 wq1 = *(const f32x4*)&wq[t * 8 + 4];
  f32x4 wk0 = *(const f32x4*)&wk[t * 8];
  f32x4 wk1 = *(const f32x4*)&wk[t * 8 + 4];
  float wqa[8] = {wq0[0], wq0[1], wq0[2], wq0[3], wq1[0], wq1[1], wq1[2], wq1[3]};
  float wka[8] = {wk0[0], wk0[1], wk0[2], wk0[3], wk1[0], wk1[1], wk1[2], wk1[3]};
  const int c0 = t * 8;
  const int h = c0 >> 7;
  const int d0 = c0 & 127;
  const int i0 = d0 >> 1;
  const float* cp = fcos + (size_t)s * (DHD / 2) + i0;
  const float* sp = fsin + (size_t)s * (DHD / 2) + i0;
  const float qscale = 0.12751744925f;  // log2(e)/sqrt(128)

  u16x8 oq, ok;
#pragma unroll
  for (int p = 0; p < 4; ++p) {
    float c = cp[p], sn = sp[p];
    float q1 = fq[2 * p] * rq * wqa[2 * p];
    float q2 = fq[2 * p + 1] * rq * wqa[2 * p + 1];
    float k1 = fk[2 * p] * rk * wka[2 * p];
    float k2 = fk[2 * p + 1] * rk * wka[2 * p + 1];
    oq[2 * p]     = f2bf((q1 * c - q2 * sn) * qscale);
    oq[2 * p + 1] = f2bf((q1 * sn + q2 * c) * qscale);
    ok[2 * p]     = f2bf(k1 * c - k2 * sn);
    ok[2 * p + 1] = f2bf(k1 * sn + k2 * c);
  }
  size_t o = (size_t)h * SLEN * DHD + (size_t)s * DHD + d0;
  *(u16x8*)&Qr[o] = oq;
  *(u16x8*)&Kr[o] = ok;
}

// ---------------------------------------------------------------------------
// MFMA flash attention (r28 + Pl stride 76 + max3 tree):
// K AND V LDS-staged (global_load_lds w16, XOR-swizzled, double-buffered) +
// XCD map.  Swapped-operand QK^T -> lane-local exp2 softmax; defer-max THR=8;
// lazy tm reduce (0 shfls/tile fast path); deferred partial lsum; packed b64
// P writes.  NEW: Pl row stride 72->76 u16 (152B = 38 banks) -- P-read bank
// base 6*l16+4g mod 32 takes 16 distinct values vs 8 at stride 72, cutting
// the PV P-read from 8-way to ~2-way conflict; max tree grouped for v_max3.
// ---------------------------------------------------------------------------
__global__ __launch_bounds__(256) void attn_fwd(const u16* __restrict__ Qr,
                                                const u16* __restrict__ Kr,
                                                const u16* __restrict__ Vt,
                                                u16* __restrict__ out) {
  const int lin = blockIdx.x;
  const int xcd = lin & 7, idx = lin >> 3;
  const int h = xcd + ((idx >> 5) << 3);
  const int qb = idx & 31;
  const int t = threadIdx.x;
  const int lane = t & 63, w = t >> 6;
  const int g = lane >> 4, l16 = lane & 15;
  const int q0 = qb * 64 + w * 16;
  const u16* Qh = Qr + (size_t)h * SLEN * DHD;
  const u16* Kh = Kr + (size_t)h * SLEN * DHD;
  const u16* Vh = Vt + (size_t)h * DHD * SLEN;

  __shared__ u16 Kl[2][64 * 128];
  __shared__ u16 Vl[2][128 * 64];
  __shared__ u16 Pl[4][16][76];   // stride 76: P-read ~2-way banks (was 8-way)

  bf16x8 aq[4];
#pragma unroll
  for (int dk = 0; dk < 4; ++dk)
    aq[dk] = *(const bf16x8*)&Qh[(size_t)(q0 + l16) * DHD + dk * 32 + g * 8];

  f32x4 o[8];
#pragma unroll
  for (int df = 0; df < 8; ++df) o[df] = (f32x4)(0.0f);
  float m = -INFINITY, lsum = 0.f;   // lsum = per-lane PARTIAL (16 kv values)

#pragma unroll
  for (int i = 0; i < 4; ++i) {
    int e = t * 8 + i * 2048;
    int kr = e >> 7, kc = (e & 127) >> 3;
    gload_lds16(Kh + (size_t)kr * DHD + ((kc ^ (kr & 7)) << 3), &Kl[0][e]);
    int vr = e >> 6, vc = (e & 63) >> 3;
    gload_lds16(Vh + (size_t)vr * SLEN + ((vc ^ (vr & 7)) << 3), &Vl[0][e]);
  }
  __syncthreads();

  int cur = 0;
  for (int kt = 0; kt < SLEN / 64; ++kt) {
    if (kt + 1 < SLEN / 64) {
      const int kv1 = (kt + 1) * 64;
#pragma unroll
      for (int i = 0; i < 4; ++i) {
        int e = t * 8 + i * 2048;
        int kr = e >> 7, kc = (e & 127) >> 3;
        gload_lds16(Kh + (size_t)(kv1 + kr) * DHD + ((kc ^ (kr & 7)) << 3),
                    &Kl[cur ^ 1][e]);
        int vr = e >> 6, vc = (e & 63) >> 3;
        gload_lds16(Vh + (size_t)vr * SLEN + kv1 + ((vc ^ (vr & 7)) << 3),
                    &Vl[cur ^ 1][e]);
      }
    }

    f32x4 s4[4];
#pragma unroll
    for (int nf = 0; nf < 4; ++nf) s4[nf] = (f32x4)(0.0f);
    __builtin_amdgcn_s_setprio(1);
#pragma unroll
    for (int nf = 0; nf < 4; ++nf) {
#pragma unroll
      for (int dk = 0; dk < 4; ++dk) {
        bf16x8 bk = *(const bf16x8*)&Kl[cur][(nf * 16 + l16) * 128 +
                                            (((dk * 4 + g) ^ (l16 & 7)) << 3)];
        s4[nf] = __builtin_amdgcn_mfma_f32_16x16x32_bf16(bk, aq[dk], s4[nf], 0, 0, 0);
      }
    }
    __builtin_amdgcn_s_setprio(0);
    // per-lane LOCAL max, grouped for v_max3 fusion (8 ops vs 15)
    float tml = fmaxf(fmaxf(s4[0][0], s4[0][1]), s4[0][2]);
    tml = fmaxf(fmaxf(tml, s4[0][3]), s4[1][0]);
    tml = fmaxf(fmaxf(tml, s4[1][1]), s4[1][2]);
    tml = fmaxf(fmaxf(tml, s4[1][3]), s4[2][0]);
    tml = fmaxf(fmaxf(tml, s4[2][1]), s4[2][2]);
    tml = fmaxf(fmaxf(tml, s4[2][3]), s4[3][0]);
    tml = fmaxf(fmaxf(tml, s4[3][1]), s4[3][2]);
    tml = fmaxf(tml, s4[3][3]);

    if (__all(tml <= m + 8.0f)) {
      // FAST PATH (defer-max): keep stale m; zero cross-lane ops.
      float ls = 0.f;
#pragma unroll
      for (int nf = 0; nf < 4; ++nf)
#pragma unroll
        for (int r = 0; r < 4; ++r) {
          float p = exp2f(s4[nf][r] - m);
          s4[nf][r] = p;
          ls += p;
        }
      lsum += ls;
    } else {
      // SLOW PATH: reduce tm across the row, rescale state.
      float tm = fmaxf(tml, __shfl_xor(tml, 16));
      tm = fmaxf(tm, __shfl_xor(tm, 32));
      const float mn = fmaxf(m, tm);
      const float corr = exp2f(m - mn);
      float ls = 0.f;
#pragma unroll
      for (int nf = 0; nf < 4; ++nf)
#pragma unroll
        for (int r = 0; r < 4; ++r) {
          float p = exp2f(s4[nf][r] - mn);
          s4[nf][r] = p;
          ls += p;
        }
      m = mn;
      lsum = lsum * corr + ls;
#pragma unroll
      for (int r = 0; r < 4; ++r) {
        float cr = __shfl(corr, 20 * g + r);
#pragma unroll
        for (int df = 0; df < 8; ++df) o[df][r] *= cr;
      }
    }
    // P -> wave-private LDS, packed 4x u16 -> one b64 store per nf
#pragma unroll
    for (int nf = 0; nf < 4; ++nf) {
      unsigned long long pk =
          (unsigned long long)f2bf(s4[nf][0]) |
          ((unsigned long long)f2bf(s4[nf][1]) << 16) |
          ((unsigned long long)f2bf(s4[nf][2]) << 32) |
          ((unsigned long long)f2bf(s4[nf][3]) << 48);
      *(unsigned long long*)&Pl[w][l16][nf * 16 + 4 * g] = pk;
    }
#pragma unroll
    for (int ks = 0; ks < 2; ++ks) {
      bf16x8 ap = *(const bf16x8*)&Pl[w][l16][ks * 32 + g * 8];
      __builtin_amdgcn_s_setprio(1);
#pragma unroll
      for (int df = 0; df < 8; ++df) {
        bf16x8 bv = *(const bf16x8*)&Vl[cur][(df * 16 + l16) * 64 +
                                             (((ks * 4 + g) ^ (l16 & 7)) << 3)];
        o[df] = __builtin_amdgcn_mfma_f32_16x16x32_bf16(ap, bv, o[df], 0, 0, 0);
      }
      __builtin_amdgcn_s_setprio(0);
    }
    __syncthreads();
    cur ^= 1;
  }

  // final cross-lane reduce of the partial lsums (row q = l16)
  lsum += __shfl_xor(lsum, 16);
  lsum += __shfl_xor(lsum, 32);
  const float invq = 1.0f / lsum;
#pragma unroll
  for (int r = 0; r < 4; ++r) {
    float ir = __shfl(invq, 20 * g + r);
#pragma unroll
    for (int df = 0; df < 8; ++df)
      out[(size_t)(q0 + 4 * g + r) * HIDN + h * DHD + df * 16 + l16] =
          f2bf(o[df][r] * ir);
  }
}

// ---------------------------------------------------------------------------
extern "C" void kernel_launch(void* const* d_in, const int* in_sizes, int n_in,
                              void* d_out, int out_size, void* d_ws, size_t ws_size,
                              hipStream_t stream) {
  (void)in_sizes; (void)n_in; (void)out_size; (void)ws_size;
  const float* hs   = (const float*)d_in[0];
  const float* fc   = (const float*)d_in[1];
  const float* fs   = (const float*)d_in[2];
  const float* wqkv = (const float*)d_in[3];
  const float* bqkv = (const float*)d_in[4];
  const float* wnq  = (const float*)d_in[5];
  const float* wnk  = (const float*)d_in[6];
  const float* wout = (const float*)d_in[7];
  const float* bout = (const float*)d_in[8];
  float* out = (float*)d_out;
  char* ws = (char*)d_ws;

  u16* wqkvT = (u16*)(ws);                  // 6144x2048 bf16 (25,165,824 B)
  u16* woutT = (u16*)(ws + 25165824);       // 2048x2048 bf16 ( 8,388,608 B)
  u16* qkv   = (u16*)(ws + 33554432);       // 2048x6144 bf16 (25,165,824 B)
  u16* hsB   = (u16*)(ws + 58720256);       // 2048x2048 bf16
  u16* Qr    = (u16*)(ws + 58720256);       // alias hsB (dead after GEMM1)
  u16* Kr    = (u16*)(ws + 67108864);       // 16x2048x128 bf16
  u16* Vt    = (u16*)(ws + 75497472);       // 16x128x2048 bf16
  u16* attnO = (u16*)(ws + 83886080);       // 2048x2048 bf16

  // 1) fused prep
  prep<<<dim3(6144), 256, 0, stream>>>(wqkv, wout, hs, wqkvT, woutT, hsB);
  // 2) QKV GEMM: single-buffer (3 blocks/CU regime) + by-chunked XCD map
  gemm_sb<<<dim3(768), 256, 0, stream>>>(hsB, wqkvT, bqkv, nullptr, qkv,
                                         2048, 6144, 2048);
  // 3) fused mid
  mid<<<dim3(3072), 256, 0, stream>>>(qkv, fc, fs, wnq, wnk, Qr, Kr, Vt);
  // 4) MFMA flash attention (all micro-opts)
  attn_fwd<<<dim3(512), 256, 0, stream>>>(Qr, Kr, Vt, attnO);
  // 5) output projection: double-buffer prefetch (1 block/CU regime)
  gemm_db<<<dim3(256), 256, 0, stream>>>(attnO, woutT, bout, out, nullptr,
                                         2048, 2048, 2048);
}